// Round 1
// baseline (166.709 us; speedup 1.0000x reference)
//
#include <hip/hip_runtime.h>
#include <math.h>

#define HW 16384
#define NC 64
#define NB 16
#define NROWS (NB * NC)   // 1024
#define KT 512            // K-chunk per joint block
#define KK 64             // inner LDS tile

// ws layout (floats):
//   [0,1024)           S_v
//   [1024,2048)        S_t
//   [2048,3072)        ent_t
//   [3072,3072+65536)  jointQ  (B x 64 x 64, Q = joint * HW^2)
//   [68608,69632)      gw

__device__ inline float wave_reduce_sum(float v) {
#pragma unroll
  for (int o = 32; o > 0; o >>= 1) v += __shfl_down(v, o, 64);
  return v;
}

__global__ __launch_bounds__(256) void stats_kernel(const float* __restrict__ vis,
                                                    const float* __restrict__ text,
                                                    float* __restrict__ ws) {
  int row = blockIdx.x;                 // 0..2047: 0..1023 vis, 1024..2047 text
  bool is_text = row >= NROWS;
  int r = is_text ? (row - NROWS) : row;
  const float4* src = (const float4*)((is_text ? text : vis) + (size_t)r * HW);

  float s = 0.f, u = 0.f;
#pragma unroll 4
  for (int i = threadIdx.x; i < HW / 4; i += 256) {
    float4 v = src[i];
    float e0 = expf(v.x), e1 = expf(v.y), e2 = expf(v.z), e3 = expf(v.w);
    s += (e0 + e1) + (e2 + e3);
    u += (e0 * v.x + e1 * v.y) + (e2 * v.z + e3 * v.w);
  }
  s = wave_reduce_sum(s);
  u = wave_reduce_sum(u);

  __shared__ float sh[8];
  int wid = threadIdx.x >> 6, lane = threadIdx.x & 63;
  if (lane == 0) { sh[wid] = s; sh[4 + wid] = u; }
  __syncthreads();
  if (threadIdx.x == 0) {
    float S = (sh[0] + sh[1]) + (sh[2] + sh[3]);
    if (!is_text) {
      ws[r] = S;
    } else {
      float U = (sh[4] + sh[5]) + (sh[6] + sh[7]);
      ws[1024 + r] = S;
      ws[2048 + r] = logf(S) - U / S;   // spatial entropy of text row
    }
  }
}

__global__ __launch_bounds__(256) void joint_kernel(const float* __restrict__ vis,
                                                    const float* __restrict__ text,
                                                    const float* __restrict__ ws,
                                                    float* __restrict__ jointQ) {
  const int chunks = HW / KT;           // 32
  int b = blockIdx.x / chunks;
  int chunk = blockIdx.x % chunks;
  int k0 = chunk * KT;

  __shared__ float lv[NC][KK + 4];      // stride 68 floats (16B-aligned rows)
  __shared__ float lt[NC][KK + 4];
  __shared__ float scv[NC], sct[NC];

  int t = threadIdx.x;
  if (t < 64)       scv[t]      = (float)HW / ws[b * 64 + t];
  else if (t < 128) sct[t - 64] = (float)HW / ws[1024 + b * 64 + (t - 64)];

  int tx = t & 15, ty = t >> 4;
  int ty4 = ty * 4, tx4 = tx * 4;
  float acc[4][4] = {};

  const float* vbase = vis  + (size_t)b * NC * HW + k0;
  const float* tbase = text + (size_t)b * NC * HW + k0;

  for (int kk = 0; kk < KT; kk += KK) {
    __syncthreads();                    // protect LDS (also covers scv/sct init)
#pragma unroll
    for (int it = 0; it < 4; ++it) {
      int r  = (t >> 4) + it * 16;
      int c4 = (t & 15) * 4;
      float4 v = *(const float4*)(vbase + (size_t)r * HW + kk + c4);
      float sv = scv[r];
      lv[r][c4 + 0] = expf(v.x) * sv;
      lv[r][c4 + 1] = expf(v.y) * sv;
      lv[r][c4 + 2] = expf(v.z) * sv;
      lv[r][c4 + 3] = expf(v.w) * sv;
      float4 w = *(const float4*)(tbase + (size_t)r * HW + kk + c4);
      float st = sct[r];
      lt[r][c4 + 0] = expf(w.x) * st;
      lt[r][c4 + 1] = expf(w.y) * st;
      lt[r][c4 + 2] = expf(w.z) * st;
      lt[r][c4 + 3] = expf(w.w) * st;
    }
    __syncthreads();
#pragma unroll
    for (int k = 0; k < KK; k += 4) {
      float4 a0 = *(const float4*)&lv[ty4 + 0][k];
      float4 a1 = *(const float4*)&lv[ty4 + 1][k];
      float4 a2 = *(const float4*)&lv[ty4 + 2][k];
      float4 a3 = *(const float4*)&lv[ty4 + 3][k];
      float4 b0 = *(const float4*)&lt[tx4 + 0][k];
      float4 b1 = *(const float4*)&lt[tx4 + 1][k];
      float4 b2 = *(const float4*)&lt[tx4 + 2][k];
      float4 b3 = *(const float4*)&lt[tx4 + 3][k];
#define ACC(i, j, A, Bv) \
      acc[i][j] += A.x * Bv.x + A.y * Bv.y + A.z * Bv.z + A.w * Bv.w;
      ACC(0,0,a0,b0) ACC(0,1,a0,b1) ACC(0,2,a0,b2) ACC(0,3,a0,b3)
      ACC(1,0,a1,b0) ACC(1,1,a1,b1) ACC(1,2,a1,b2) ACC(1,3,a1,b3)
      ACC(2,0,a2,b0) ACC(2,1,a2,b1) ACC(2,2,a2,b2) ACC(2,3,a2,b3)
      ACC(3,0,a3,b0) ACC(3,1,a3,b1) ACC(3,2,a3,b2) ACC(3,3,a3,b3)
#undef ACC
    }
  }

  float* J = jointQ + (size_t)b * 4096;
#pragma unroll
  for (int i = 0; i < 4; ++i)
#pragma unroll
    for (int j = 0; j < 4; ++j)
      atomicAdd(&J[(ty4 + i) * 64 + (tx4 + j)], acc[i][j]);
}

__global__ __launch_bounds__(256) void mi_gw_kernel(const float* __restrict__ jointQ,
                                                    const float* __restrict__ ent_t,
                                                    float* __restrict__ gw) {
  int b = blockIdx.x;
  const float* J = jointQ + (size_t)b * 4096;
  float part = 0.f;
  for (int i = threadIdx.x; i < 4096; i += 256) {
    float q = J[i];
    part += q * logf(q + 1e-9f);        // log(joint*HW^2 + eps)
  }
  part = wave_reduce_sum(part);
  __shared__ float sh[4];
  __shared__ float mi_sh;
  int wid = threadIdx.x >> 6, lane = threadIdx.x & 63;
  if (lane == 0) sh[wid] = part;
  __syncthreads();
  if (threadIdx.x == 0) {
    float s = (sh[0] + sh[1]) + (sh[2] + sh[3]);
    mi_sh = s * (1.0f / ((float)HW * (float)HW));   // mi[b]
  }
  __syncthreads();
  if (threadIdx.x < 64) {
    int idx = b * 64 + threadIdx.x;
    float z = 1.0f - ent_t[idx] + 0.5f * mi_sh;
    gw[idx] = 1.0f / (1.0f + expf(-z));
  }
}

__global__ __launch_bounds__(256) void enhance_kernel(const float4* __restrict__ vis,
                                                      const float4* __restrict__ text,
                                                      const float* __restrict__ gw,
                                                      float4* __restrict__ out) {
  const size_t total4 = (size_t)NB * NC * HW / 4;   // 4194304
  for (size_t i = (size_t)blockIdx.x * 256 + threadIdx.x; i < total4;
       i += (size_t)gridDim.x * 256) {
    float4 v = vis[i];
    float4 t = text[i];
    float g = gw[i >> 12];              // 4096 float4 per (b,c) row
    out[i] = make_float4(v.x + g * t.x, v.y + g * t.y,
                         v.z + g * t.z, v.w + g * t.w);
  }
}

extern "C" void kernel_launch(void* const* d_in, const int* in_sizes, int n_in,
                              void* d_out, int out_size, void* d_ws, size_t ws_size,
                              hipStream_t stream) {
  const float* vis  = (const float*)d_in[0];
  const float* text = (const float*)d_in[1];
  float* out = (float*)d_out;
  float* ws  = (float*)d_ws;

  float* jointQ = ws + 3072;
  float* ent_t  = ws + 2048;
  float* gw     = ws + 3072 + 65536;

  hipMemsetAsync(jointQ, 0, 65536 * sizeof(float), stream);

  stats_kernel<<<2 * NROWS, 256, 0, stream>>>(vis, text, ws);
  joint_kernel<<<NB * (HW / KT), 256, 0, stream>>>(vis, text, ws, jointQ);
  mi_gw_kernel<<<NB, 256, 0, stream>>>(jointQ, ent_t, gw);
  enhance_kernel<<<2048, 256, 0, stream>>>((const float4*)vis, (const float4*)text,
                                           gw, (float4*)out);
}

// Round 2
// 71.417 us; speedup vs baseline: 2.3343x; 2.3343x over previous
//
#include <hip/hip_runtime.h>
#include <math.h>

#define HW 16384
#define NC 64
#define NB 16
#define CH 32               // k-chunks per batch (grid = NB*CH = 512 blocks)
#define KB (HW / CH)        // 512 k per block
#define KC 64               // k per LDS stage
#define NIT (KB / KC)       // 8 stages per block

// ws layout (floats):
//   [0,1024)           S_v   (sum exp(vis) per row)
//   [1024,2048)        S_t
//   [2048,3072)        U_t   (sum exp(text)*text per row)
//   [3072,68608)       J_raw (B x 64 x 64, sum exp(v)exp(t))
//   [68608,69632)      gw

typedef __attribute__((ext_vector_type(8))) short bf16x8;
typedef __attribute__((ext_vector_type(8))) unsigned short u16x8;
typedef __attribute__((ext_vector_type(4))) float f32x4;

__device__ inline unsigned short f2bf(float x) {
  union { float f; unsigned u; } v; v.f = x;
  unsigned r = v.u + 0x7FFFu + ((v.u >> 16) & 1u);   // RNE (no NaN here: exp>0)
  return (unsigned short)(r >> 16);
}

__device__ inline float wave_reduce_sum(float v) {
#pragma unroll
  for (int o = 32; o > 0; o >>= 1) v += __shfl_down(v, o, 64);
  return v;
}

// LDS tile: 64 rows x 64 bf16, row stride 128B. XOR-swizzle 16B slots:
// slot(r, ko16) = ko16 ^ (r & 7)  -> ds_read_b128 across 16 rows = 2-way max.
__device__ inline int lds_off(int r, int ko16) {
  return r * 64 + ((ko16 ^ (r & 7)) << 3);   // in ushort units
}

__global__ __launch_bounds__(256) void joint_fused(const float* __restrict__ vis,
                                                   const float* __restrict__ text,
                                                   float* __restrict__ ws) {
  const int b = blockIdx.x / CH;
  const int chunk = blockIdx.x % CH;
  const int k0 = chunk * KB;

  __shared__ __align__(16) unsigned short lv[64 * 64];
  __shared__ __align__(16) unsigned short lt[64 * 64];

  const int t = threadIdx.x;
  const int w = t >> 6;           // wave 0..3
  const int l = t & 63;
  const int r = w * 16 + (l >> 2);  // staging row 0..63
  const int kq = l & 3;             // 16-float quarter of the 64-k stage

  const float* vrow = vis  + ((size_t)b * NC + r) * HW + k0 + kq * 16;
  const float* trow = text + ((size_t)b * NC + r) * HW + k0 + kq * 16;

  float4 rv0, rv1, rv2, rv3, rt0, rt1, rt2, rt3;
  {
    const float4* pv = (const float4*)vrow;
    const float4* pt = (const float4*)trow;
    rv0 = pv[0]; rv1 = pv[1]; rv2 = pv[2]; rv3 = pv[3];
    rt0 = pt[0]; rt1 = pt[1]; rt2 = pt[2]; rt3 = pt[3];
  }

  float sv = 0.f, st = 0.f, ut = 0.f;
  f32x4 acc0 = {0.f,0.f,0.f,0.f}, acc1 = {0.f,0.f,0.f,0.f};
  f32x4 acc2 = {0.f,0.f,0.f,0.f}, acc3 = {0.f,0.f,0.f,0.f};

  const int mrow = w * 16 + (l & 15);  // A row this wave reads
  const int kol  = l >> 4;             // 0..3 (k 16B-slot within k-step)

  for (int it = 0; it < NIT; ++it) {
    // --- exp + cvt + stats (consumes prefetched regs) ---
    u16x8 ev0, ev1, et0, et1;
#define DOV(V, DST, J0) { \
    float e0=__expf(V.x), e1=__expf(V.y), e2=__expf(V.z), e3=__expf(V.w); \
    sv += (e0+e1)+(e2+e3); \
    DST[J0+0]=(short)f2bf(e0); DST[J0+1]=(short)f2bf(e1); \
    DST[J0+2]=(short)f2bf(e2); DST[J0+3]=(short)f2bf(e3); }
#define DOT(V, DST, J0) { \
    float e0=__expf(V.x), e1=__expf(V.y), e2=__expf(V.z), e3=__expf(V.w); \
    st += (e0+e1)+(e2+e3); \
    ut += (e0*V.x+e1*V.y)+(e2*V.z+e3*V.w); \
    DST[J0+0]=(short)f2bf(e0); DST[J0+1]=(short)f2bf(e1); \
    DST[J0+2]=(short)f2bf(e2); DST[J0+3]=(short)f2bf(e3); }
    DOV(rv0, ev0, 0) DOV(rv1, ev0, 4) DOV(rv2, ev1, 0) DOV(rv3, ev1, 4)
    DOT(rt0, et0, 0) DOT(rt1, et0, 4) DOT(rt2, et1, 0) DOT(rt3, et1, 4)
#undef DOV
#undef DOT

    __syncthreads();   // all waves finished reading LDS of previous stage

    // --- stage to LDS (swizzled) ---
    *reinterpret_cast<u16x8*>(&lv[lds_off(r, kq*2    )]) = ev0;
    *reinterpret_cast<u16x8*>(&lv[lds_off(r, kq*2 + 1)]) = ev1;
    *reinterpret_cast<u16x8*>(&lt[lds_off(r, kq*2    )]) = et0;
    *reinterpret_cast<u16x8*>(&lt[lds_off(r, kq*2 + 1)]) = et1;

    // --- prefetch next stage (stays in flight across the raw barrier) ---
    if (it + 1 < NIT) {
      const float4* pv = (const float4*)(vrow + (it + 1) * KC);
      const float4* pt = (const float4*)(trow + (it + 1) * KC);
      rv0 = pv[0]; rv1 = pv[1]; rv2 = pv[2]; rv3 = pv[3];
      rt0 = pt[0]; rt1 = pt[1]; rt2 = pt[2]; rt3 = pt[3];
    }

    asm volatile("s_waitcnt lgkmcnt(0)" ::: "memory");  // ds_writes visible
    __builtin_amdgcn_s_barrier();                        // no vmcnt drain
    asm volatile("" ::: "memory");

    // --- MFMA: wave w owns A-rows [16w,16w+16); 4 B tiles cover n=0..63 ---
#pragma unroll
    for (int s = 0; s < 2; ++s) {
      int ko = s * 4 + kol;
      bf16x8 a = *reinterpret_cast<const bf16x8*>(&lv[lds_off(mrow, ko)]);
      bf16x8 b0 = *reinterpret_cast<const bf16x8*>(&lt[lds_off( 0 + (l & 15), ko)]);
      bf16x8 b1 = *reinterpret_cast<const bf16x8*>(&lt[lds_off(16 + (l & 15), ko)]);
      bf16x8 b2 = *reinterpret_cast<const bf16x8*>(&lt[lds_off(32 + (l & 15), ko)]);
      bf16x8 b3 = *reinterpret_cast<const bf16x8*>(&lt[lds_off(48 + (l & 15), ko)]);
      acc0 = __builtin_amdgcn_mfma_f32_16x16x32_bf16(a, b0, acc0, 0, 0, 0);
      acc1 = __builtin_amdgcn_mfma_f32_16x16x32_bf16(a, b1, acc1, 0, 0, 0);
      acc2 = __builtin_amdgcn_mfma_f32_16x16x32_bf16(a, b2, acc2, 0, 0, 0);
      acc3 = __builtin_amdgcn_mfma_f32_16x16x32_bf16(a, b3, acc3, 0, 0, 0);
    }
  }

  // --- stats: quad lanes (same row) reduce, one atomic per row ---
  sv += __shfl_xor(sv, 1, 64); sv += __shfl_xor(sv, 2, 64);
  st += __shfl_xor(st, 1, 64); st += __shfl_xor(st, 2, 64);
  ut += __shfl_xor(ut, 1, 64); ut += __shfl_xor(ut, 2, 64);
  if ((l & 3) == 0) {
    atomicAdd(&ws[b * 64 + r], sv);
    atomicAdd(&ws[1024 + b * 64 + r], st);
    atomicAdd(&ws[2048 + b * 64 + r], ut);
  }

  // --- J_raw accumulate: C/D layout col=l&15, row=(l>>4)*4+reg (m89) ---
  float* J = ws + 3072 + (size_t)b * 4096;
  const int m0 = w * 16 + (l >> 4) * 4;
  const int n0 = l & 15;
#pragma unroll
  for (int reg = 0; reg < 4; ++reg) {
    atomicAdd(&J[(m0 + reg) * 64 +  0 + n0], acc0[reg]);
    atomicAdd(&J[(m0 + reg) * 64 + 16 + n0], acc1[reg]);
    atomicAdd(&J[(m0 + reg) * 64 + 32 + n0], acc2[reg]);
    atomicAdd(&J[(m0 + reg) * 64 + 48 + n0], acc3[reg]);
  }
}

__global__ __launch_bounds__(256) void mi_gw_kernel(const float* __restrict__ ws,
                                                    float* __restrict__ gw) {
  const int b = blockIdx.x;
  const int t = threadIdx.x;
  __shared__ float sSv[64], sSt[64];
  if (t < 64) sSv[t] = ws[b * 64 + t];
  else if (t < 128) sSt[t - 64] = ws[1024 + b * 64 + (t - 64)];
  __syncthreads();

  const float* J = ws + 3072 + (size_t)b * 4096;
  const float HW2 = (float)HW * (float)HW;
  float part = 0.f;
  for (int i = t; i < 4096; i += 256) {
    int c = i >> 6, d = i & 63;
    float q = J[i] * (HW2 / (sSv[c] * sSt[d]));   // Q = HW^2 * joint
    part += q * __logf(q + 1e-9f);
  }
  part = wave_reduce_sum(part);
  __shared__ float sh[4];
  __shared__ float mi_sh;
  int wid = t >> 6, lane = t & 63;
  if (lane == 0) sh[wid] = part;
  __syncthreads();
  if (t == 0) mi_sh = ((sh[0] + sh[1]) + (sh[2] + sh[3])) / HW2;
  __syncthreads();
  if (t < 64) {
    float S = sSt[t];
    float U = ws[2048 + b * 64 + t];
    float ent = __logf(S) - U / S;                // text spatial entropy
    float z = 1.0f - ent + 0.5f * mi_sh;
    gw[b * 64 + t] = 1.0f / (1.0f + __expf(-z));
  }
}

__global__ __launch_bounds__(256) void enhance_kernel(const float4* __restrict__ vis,
                                                      const float4* __restrict__ text,
                                                      const float* __restrict__ gw,
                                                      float4* __restrict__ out) {
  const size_t total4 = (size_t)NB * NC * HW / 4;   // 4194304
  for (size_t i = (size_t)blockIdx.x * 256 + threadIdx.x; i < total4;
       i += (size_t)gridDim.x * 256) {
    float4 v = vis[i];
    float4 t = text[i];
    float g = gw[i >> 12];              // 4096 float4 per (b,c) row
    out[i] = make_float4(v.x + g * t.x, v.y + g * t.y,
                         v.z + g * t.z, v.w + g * t.w);
  }
}

extern "C" void kernel_launch(void* const* d_in, const int* in_sizes, int n_in,
                              void* d_out, int out_size, void* d_ws, size_t ws_size,
                              hipStream_t stream) {
  const float* vis  = (const float*)d_in[0];
  const float* text = (const float*)d_in[1];
  float* out = (float*)d_out;
  float* ws  = (float*)d_ws;
  float* gw  = ws + 68608;

  // zero S_v, S_t, U_t, J_raw
  hipMemsetAsync(ws, 0, 68608 * sizeof(float), stream);

  joint_fused<<<NB * CH, 256, 0, stream>>>(vis, text, ws);
  mi_gw_kernel<<<NB, 256, 0, stream>>>(ws, gw);
  enhance_kernel<<<2048, 256, 0, stream>>>((const float4*)vis, (const float4*)text,
                                           gw, (float4*)out);
}